// Round 10
// baseline (227.072 us; speedup 1.0000x reference)
//
#include <hip/hip_runtime.h>
#include <hip/hip_bf16.h>

#define NPAIR 4096
#define DIM   768
#define N2    8192
#define BM    256            // block tile 256x256; 8 waves as 2x4 of 128x64
#define BK    128            // K tile (fp8 bytes = elems); rows are 128B
#define NKT   (DIM / BK)     // 6 K-tiles per col-tile
#define NCT   4              // col-tiles per block
#define TOT   (NKT * NCT)    // 24 K-tile iterations
#define NPANEL (N2 / BM)     // 32 row panels
#define NSTRIP 8             // col strips (each 4 x 256 cols)

constexpr float INV_T = 1.0f / 0.07f;  // also the fixed softmax max M

typedef float f32x16 __attribute__((ext_vector_type(16)));
#define AS1 __attribute__((address_space(1)))
#define AS3 __attribute__((address_space(3)))

// ---------------- normalize: one wave per row, fp32 in -> fp8 e4m3 out ------
__global__ void knorm(const float* __restrict__ z1, const float* __restrict__ z2,
                      unsigned char* __restrict__ zq) {
    const int row  = blockIdx.x * 4 + (threadIdx.x >> 6);
    const int lane = threadIdx.x & 63;
    const float* src = (row < NPAIR) ? (z1 + (size_t)row * DIM)
                                     : (z2 + (size_t)(row - NPAIR) * DIM);
    float4 v[3];
    float ss = 0.f;
#pragma unroll
    for (int i = 0; i < 3; ++i) {
        v[i] = reinterpret_cast<const float4*>(src)[lane + 64 * i];
        ss += v[i].x * v[i].x + v[i].y * v[i].y + v[i].z * v[i].z + v[i].w * v[i].w;
    }
#pragma unroll
    for (int off = 32; off; off >>= 1) ss += __shfl_xor(ss, off);
    const float scale = 1.0f / fmaxf(sqrtf(ss), 1e-12f);
    unsigned int* dst = reinterpret_cast<unsigned int*>(zq + (size_t)row * DIM);
#pragma unroll
    for (int i = 0; i < 3; ++i) {
        unsigned int u = 0;
        u = __builtin_amdgcn_cvt_pk_fp8_f32(v[i].x * scale, v[i].y * scale, u, false);
        u = __builtin_amdgcn_cvt_pk_fp8_f32(v[i].z * scale, v[i].w * scale, u, true);
        dst[lane + 64 * i] = u;
    }
}

// ---------------- positive-pair dots from fp8 (consistent with klse) --------
__global__ void kpos(const unsigned char* __restrict__ zq, float* __restrict__ pos) {
    const int pair = blockIdx.x * 4 + (threadIdx.x >> 6);
    const int lane = threadIdx.x & 63;
    const unsigned int* a = reinterpret_cast<const unsigned int*>(zq + (size_t)pair * DIM);
    const unsigned int* b = reinterpret_cast<const unsigned int*>(zq + (size_t)(pair + NPAIR) * DIM);
    float s = 0.f;
#pragma unroll
    for (int i = 0; i < 3; ++i) {
        const unsigned int ua = a[lane + 64 * i];
        const unsigned int ub = b[lane + 64 * i];
        s += __builtin_amdgcn_cvt_f32_fp8(ua, 0) * __builtin_amdgcn_cvt_f32_fp8(ub, 0);
        s += __builtin_amdgcn_cvt_f32_fp8(ua, 1) * __builtin_amdgcn_cvt_f32_fp8(ub, 1);
        s += __builtin_amdgcn_cvt_f32_fp8(ua, 2) * __builtin_amdgcn_cvt_f32_fp8(ub, 2);
        s += __builtin_amdgcn_cvt_f32_fp8(ua, 3) * __builtin_amdgcn_cvt_f32_fp8(ub, 3);
    }
#pragma unroll
    for (int off = 32; off; off >>= 1) s += __shfl_xor(s, off);
    if (lane == 0) pos[pair] = s * INV_T;
}

// ---------------- main: 256^2 tile, 4-phase interleaved dbuf pipeline -------
// 8 waves (2x4), per-wave 128x64 output via acc[4][2] of mfma 32x32x16 fp8.
// Per K-tile: 4 phases {12 ds_read_b64 | 1-2 global_load_lds -> barrier ->
// setprio(1) 16 MFMA setprio(0) -> barrier}; stage issues confined to phases
// 0-1 so the single per-tile vmcnt(0) (phase 3) is ~free. LDS 128KB dbuf.
__global__ __launch_bounds__(512, 2) void klse(const unsigned char* __restrict__ zq,
                                               float* __restrict__ rowsum) {
    extern __shared__ __align__(16) char smem[];
    float* rs = (float*)(smem + 131072);           // 256 f32 row partials
    const int tid  = threadIdx.x;
    const int wave = tid >> 6;
    const int lane = tid & 63;
    const int wr = wave >> 2;          // 0..1  (128-row half)
    const int wc = wave & 3;           // 0..3  (64-col quarter)
    const int hi = lane >> 5, rlo = lane & 31;
    const int rb = blockIdx.x * BM;
    const int cbase = blockIdx.y * (NCT * BM);
    const int sw = rlo & 7;

    // LDS element offsets (bytes) of fragment rows
    int aOff[4], bOff[2];
#pragma unroll
    for (int m = 0; m < 4; ++m) aOff[m] = (wr * 128 + m * 32 + rlo) * BK + hi * 8;
#pragma unroll
    for (int n = 0; n < 2; ++n) bOff[n] = (wc * 64 + n * 32 + rlo) * BK + hi * 8;

    // init row partials
    if (tid < 256) rs[tid] = 0.f;

    // prologue: stage tile (ct=0, kt=0) into buffer 0
#pragma unroll
    for (int j = 0; j < 4; ++j) {
        const int g = j * 512 + tid;               // granule (16B), [0,2048)
        const int r = g >> 3, slot = g & 7;
        const int kc = (slot ^ (r & 7)) << 4;      // kt=0
        __builtin_amdgcn_global_load_lds(
            (const AS1 unsigned int*)(zq + (size_t)(rb + r) * DIM + kc),
            (AS3 unsigned int*)(smem + g * 16), 16, 0, 0);
        __builtin_amdgcn_global_load_lds(
            (const AS1 unsigned int*)(zq + (size_t)(cbase + r) * DIM + kc),
            (AS3 unsigned int*)(smem + 65536 + g * 16), 16, 0, 0);
    }
    asm volatile("s_waitcnt vmcnt(0)" ::: "memory");
    __builtin_amdgcn_s_barrier();

    f32x16 acc[4][2];
#pragma unroll
    for (int m = 0; m < 4; ++m) { acc[m][0] = f32x16{}; acc[m][1] = f32x16{}; }

    int tglob = 0;
    for (int ct = 0; ct < NCT; ++ct) {
        const int c0 = cbase + ct * BM;
        for (int kt = 0; kt < NKT; ++kt, ++tglob) {
            const int cur = tglob & 1;
            const char* curA = smem + cur * 32768;
            const char* curB = smem + 65536 + cur * 32768;
            char* nxtA = smem + (cur ^ 1) * 32768;
            char* nxtB = smem + 65536 + (cur ^ 1) * 32768;
            const bool has_next = (tglob < TOT - 1);
            const int ktn = (kt == NKT - 1) ? 0 : kt + 1;
            const int c0n = (kt == NKT - 1) ? c0 + BM : c0;

#pragma unroll
            for (int p = 0; p < 4; ++p) {
                // fragments for K-steps 2p, 2p+1 (12 x ds_read_b64)
                long a[4][2], b[2][2];
#pragma unroll
                for (int j = 0; j < 2; ++j) {
                    const int so = ((2 * p + j) ^ sw) << 4;
#pragma unroll
                    for (int m = 0; m < 4; ++m)
                        a[m][j] = *reinterpret_cast<const long*>(curA + aOff[m] + so);
#pragma unroll
                    for (int n = 0; n < 2; ++n)
                        b[n][j] = *reinterpret_cast<const long*>(curB + bOff[n] + so);
                }
                // stage next tile: 4 gloads in phases 0 and 1 only
                if (p < 2 && has_next) {
#pragma unroll
                    for (int j = 0; j < 2; ++j) {
                        const int g = (2 * p + j) * 512 + tid;
                        const int r = g >> 3, slot = g & 7;
                        const int kc = ktn * BK + ((slot ^ (r & 7)) << 4);
                        __builtin_amdgcn_global_load_lds(
                            (const AS1 unsigned int*)(zq + (size_t)(rb + r) * DIM + kc),
                            (AS3 unsigned int*)(nxtA + g * 16), 16, 0, 0);
                        __builtin_amdgcn_global_load_lds(
                            (const AS1 unsigned int*)(zq + (size_t)(c0n + r) * DIM + kc),
                            (AS3 unsigned int*)(nxtB + g * 16), 16, 0, 0);
                    }
                }
                __builtin_amdgcn_s_barrier();
                __builtin_amdgcn_s_setprio(1);
#pragma unroll
                for (int j = 0; j < 2; ++j)
#pragma unroll
                    for (int m = 0; m < 4; ++m)
#pragma unroll
                        for (int n = 0; n < 2; ++n)
                            acc[m][n] = __builtin_amdgcn_mfma_f32_32x32x16_fp8_fp8(
                                a[m][j], b[n][j], acc[m][n], 0, 0, 0);
                __builtin_amdgcn_s_setprio(0);
                if (p == 3) asm volatile("s_waitcnt vmcnt(0)" ::: "memory");
                __builtin_amdgcn_s_barrier();
            }
        }

        // ---------- epilogue for this col-tile: exp, mask, reduce -----------
        const bool on_diag = (c0 == rb);
#pragma unroll
        for (int m = 0; m < 4; ++m) {
            const int rbase = wr * 128 + m * 32 + 4 * hi;   // row within panel
            float ps[16];
#pragma unroll
            for (int r = 0; r < 16; ++r) {
                float e0 = __expf((acc[m][0][r] - 1.0f) * INV_T);
                float e1 = __expf((acc[m][1][r] - 1.0f) * INV_T);
                if (on_diag) {
                    const int rg = rbase + (r & 3) + 8 * (r >> 2);
                    if (rg == wc * 64 + rlo)      e0 = 0.f;
                    if (rg == wc * 64 + 32 + rlo) e1 = 0.f;
                }
                ps[r] = e0 + e1;
            }
#pragma unroll
            for (int r = 0; r < 16; ++r)
#pragma unroll
                for (int msk = 1; msk < 32; msk <<= 1)
                    ps[r] += __shfl_xor(ps[r], msk);
            if (rlo == 0) {
#pragma unroll
                for (int r = 0; r < 16; ++r)
                    atomicAdd(&rs[rbase + (r & 3) + 8 * (r >> 2)], ps[r]);
            }
            acc[m][0] = f32x16{};
            acc[m][1] = f32x16{};
        }
    }

    // final flush: block-exclusive? no — 8 strip-blocks share a panel: atomic
    __syncthreads();
    if (tid < 256) atomicAdd(&rowsum[rb + tid], rs[tid]);
}

// ---------------- final: loss = mean(M + log S_i - pos) ---------------------
__global__ void kfinal(const float* __restrict__ rowsum, const float* __restrict__ pos,
                       float* __restrict__ out) {
    __shared__ float red[8];
    const int tid = threadIdx.x;
    float s = 0.f;
    for (int i = tid; i < N2; i += 512) {
        const int p = (i < NPAIR) ? i : i - NPAIR;
        s += INV_T + __logf(rowsum[i]) - pos[p];
    }
#pragma unroll
    for (int off = 32; off; off >>= 1) s += __shfl_xor(s, off);
    if ((tid & 63) == 0) red[tid >> 6] = s;
    __syncthreads();
    if (tid == 0) {
        float t = 0.f;
#pragma unroll
        for (int w = 0; w < 8; ++w) t += red[w];
        out[0] = t / (float)N2;
    }
}

extern "C" void kernel_launch(void* const* d_in, const int* in_sizes, int n_in,
                              void* d_out, int out_size, void* d_ws, size_t ws_size,
                              hipStream_t stream) {
    const float* z1 = (const float*)d_in[0];
    const float* z2 = (const float*)d_in[1];
    unsigned char* zq = (unsigned char*)d_ws;                         // 8192*768 fp8
    float* rowsum = (float*)((char*)d_ws + (size_t)N2 * DIM);         // 8192 f32
    float* pos = rowsum + N2;                                         // 4096 f32
    float* out = (float*)d_out;

    static bool attr_set = false;
    if (!attr_set) {
        hipFuncSetAttribute((const void*)klse,
                            hipFuncAttributeMaxDynamicSharedMemorySize, 132096);
        attr_set = true;
    }

    hipLaunchKernelGGL(knorm, dim3(N2 / 4), dim3(256), 0, stream, z1, z2, zq);
    hipLaunchKernelGGL(kpos, dim3(NPAIR / 4), dim3(256), 0, stream, zq, pos);
    hipMemsetAsync(rowsum, 0, N2 * sizeof(float), stream);
    hipLaunchKernelGGL(klse, dim3(NPANEL, NSTRIP), dim3(512), 132096, stream, zq, rowsum);
    hipLaunchKernelGGL(kfinal, dim3(1), dim3(512), 0, stream, rowsum, pos, out);
}

// Round 11
// 156.638 us; speedup vs baseline: 1.4497x; 1.4497x over previous
//
#include <hip/hip_runtime.h>
#include <hip/hip_bf16.h>

#define NPAIR 4096
#define DIM   768            // fp8: 768 bytes per row
#define N2    8192
#define BM    128            // block rows (4 waves as 2x2, each 64x64)
#define BNB   128            // block cols per col-block
#define KBLK  64             // K tile bytes -> A,B tiles 8KB each; dbuf = 32KB
#define KITER (DIM / KBLK)   // 12
#define NSTRIP 16            // grid.y
#define CPB   ((N2 / BNB) / NSTRIP)    // 4 col-blocks per strip
#define NBI   (N2 / BM)      // 64
#define TOT   (CPB * KITER)  // 48 K-tile iterations per block

constexpr float INV_T = 1.0f / 0.07f;  // also the fixed softmax max M

typedef float f32x16 __attribute__((ext_vector_type(16)));
#define AS1 __attribute__((address_space(1)))
#define AS3 __attribute__((address_space(3)))

// ---------------- normalize: one wave per row, fp32 in -> fp8 e4m3 out ------
__global__ void knorm(const float* __restrict__ z1, const float* __restrict__ z2,
                      unsigned char* __restrict__ zq) {
    const int row  = blockIdx.x * 4 + (threadIdx.x >> 6);
    const int lane = threadIdx.x & 63;
    const float* src = (row < NPAIR) ? (z1 + (size_t)row * DIM)
                                     : (z2 + (size_t)(row - NPAIR) * DIM);
    float4 v[3];
    float ss = 0.f;
#pragma unroll
    for (int i = 0; i < 3; ++i) {
        v[i] = reinterpret_cast<const float4*>(src)[lane + 64 * i];
        ss += v[i].x * v[i].x + v[i].y * v[i].y + v[i].z * v[i].z + v[i].w * v[i].w;
    }
#pragma unroll
    for (int off = 32; off; off >>= 1) ss += __shfl_xor(ss, off);
    const float scale = 1.0f / fmaxf(sqrtf(ss), 1e-12f);
    unsigned int* dst = reinterpret_cast<unsigned int*>(zq + (size_t)row * DIM);
#pragma unroll
    for (int i = 0; i < 3; ++i) {
        unsigned int u = 0;
        u = __builtin_amdgcn_cvt_pk_fp8_f32(v[i].x * scale, v[i].y * scale, u, false);
        u = __builtin_amdgcn_cvt_pk_fp8_f32(v[i].z * scale, v[i].w * scale, u, true);
        dst[lane + 64 * i] = u;
    }
}

// ---------------- positive-pair dots from fp8 (consistent with klse) --------
__global__ void kpos(const unsigned char* __restrict__ zq, float* __restrict__ pos) {
    const int pair = blockIdx.x * 4 + (threadIdx.x >> 6);
    const int lane = threadIdx.x & 63;
    const unsigned int* a = reinterpret_cast<const unsigned int*>(zq + (size_t)pair * DIM);
    const unsigned int* b = reinterpret_cast<const unsigned int*>(zq + (size_t)(pair + NPAIR) * DIM);
    float s = 0.f;
#pragma unroll
    for (int i = 0; i < 3; ++i) {
        const unsigned int ua = a[lane + 64 * i];
        const unsigned int ub = b[lane + 64 * i];
        s += __builtin_amdgcn_cvt_f32_fp8(ua, 0) * __builtin_amdgcn_cvt_f32_fp8(ub, 0);
        s += __builtin_amdgcn_cvt_f32_fp8(ua, 1) * __builtin_amdgcn_cvt_f32_fp8(ub, 1);
        s += __builtin_amdgcn_cvt_f32_fp8(ua, 2) * __builtin_amdgcn_cvt_f32_fp8(ub, 2);
        s += __builtin_amdgcn_cvt_f32_fp8(ua, 3) * __builtin_amdgcn_cvt_f32_fp8(ub, 3);
    }
#pragma unroll
    for (int off = 32; off; off >>= 1) s += __shfl_xor(s, off);
    if (lane == 0) pos[pair] = s * INV_T;
}

// ---------------- main: R8 engine + T3 minimum-2-phase double buffer --------
// Per iter: STAGE(next tile -> buf^1) issued FIRST, then ds_read+MFMA on
// buf, then ONE vmcnt(0)+s_barrier (drain covered by the compute between
// issue and wait). dbuf stays 32KB (KBLK=64) -> 3 blocks/CU preserved.
// __launch_bounds__(256,3) caps regs at ~170 so occupancy can't drop.
__global__ __launch_bounds__(256, 3) void klse(const unsigned char* __restrict__ zq,
                                               float* __restrict__ rowsum) {
    __shared__ __align__(16) unsigned char As[2][BM * KBLK];   // 2 x 8 KB
    __shared__ __align__(16) unsigned char Bs[2][BM * KBLK];   // 2 x 8 KB
    const int tid  = threadIdx.x;
    const int wave = tid >> 6;
    const int lane = tid & 63;
    const int wr = wave >> 1, wc = wave & 1;
    const int hi = lane >> 5, rlo = lane & 31;
    const int bi = blockIdx.x;
    const int rb = bi * BM;

    const int sw  = rlo & 3;                     // read-side granule swizzle (4 granules/row)
    const int raA = (wr * 64 + rlo) * KBLK;      // A sub 0 row base (bytes)
    const int raB = raA + 32 * KBLK;             // A sub 1
    const int caA = (wc * 64 + rlo) * KBLK;      // B sub 0 col base
    const int caB = caA + 32 * KBLK;             // B sub 1

    // stage K-tile (ct,kt) into buffer buf: 512 granules of 16B per matrix
    auto stage = [&](int ct, int kt, int buf) {
        const int c0 = (blockIdx.y * CPB + ct) * BNB;
        const int koff = kt * KBLK;
#pragma unroll
        for (int i = 0; i < 2; ++i) {
            const int g = i * 256 + tid;         // granule in [0,512)
            const int r = g >> 2, s = g & 3;
            const int ks = koff + ((s ^ (r & 3)) << 4);
            __builtin_amdgcn_global_load_lds(
                (const AS1 unsigned int*)(zq + (size_t)(rb + r) * DIM + ks),
                (AS3 unsigned int*)(&As[buf][g * 16]), 16, 0, 0);
            __builtin_amdgcn_global_load_lds(
                (const AS1 unsigned int*)(zq + (size_t)(c0 + r) * DIM + ks),
                (AS3 unsigned int*)(&Bs[buf][g * 16]), 16, 0, 0);
        }
    };

    f32x16 acc00 = {}, acc01 = {}, acc10 = {}, acc11 = {};

    stage(0, 0, 0);
    asm volatile("s_waitcnt vmcnt(0)" ::: "memory");
    __builtin_amdgcn_s_barrier();

    int ct = 0, kt = 0;
    for (int it = 0; it < TOT; ++it) {
        const int cur = it & 1;
        int nct = ct, nkt = kt + 1;
        if (nkt == KITER) { nkt = 0; ++nct; }
        if (it + 1 < TOT) stage(nct, nkt, cur ^ 1);   // issue next-tile loads FIRST

        // compute on buf[cur]: 4 K-steps x 2x2 subtiles
#pragma unroll
        for (int ts = 0; ts < 4; ++ts) {
            const int so = ((ts ^ sw) << 4) + (hi << 3);  // swizzled octet offset
            long a0 = *reinterpret_cast<const long*>(&As[cur][raA + so]);
            long a1 = *reinterpret_cast<const long*>(&As[cur][raB + so]);
            long b0 = *reinterpret_cast<const long*>(&Bs[cur][caA + so]);
            long b1 = *reinterpret_cast<const long*>(&Bs[cur][caB + so]);
            acc00 = __builtin_amdgcn_mfma_f32_32x32x16_fp8_fp8(a0, b0, acc00, 0, 0, 0);
            acc01 = __builtin_amdgcn_mfma_f32_32x32x16_fp8_fp8(a0, b1, acc01, 0, 0, 0);
            acc10 = __builtin_amdgcn_mfma_f32_32x32x16_fp8_fp8(a1, b0, acc10, 0, 0, 0);
            acc11 = __builtin_amdgcn_mfma_f32_32x32x16_fp8_fp8(a1, b1, acc11, 0, 0, 0);
        }

        asm volatile("s_waitcnt vmcnt(0)" ::: "memory");  // next buffer landed
        __builtin_amdgcn_s_barrier();                     // all reads of buf^1 done too

        if (kt == KITER - 1) {
            // ---------- epilogue for col-block ct: exp, mask, reduce --------
            const int cblk = blockIdx.y * CPB + ct;
            const bool on_diag = (cblk == bi);
            const int row0b = rb + wr * 64 + 4 * hi;
            const int colg  = cblk * BNB + wc * 64 + rlo;
            float ps0[16], ps1[16];
#pragma unroll
            for (int r = 0; r < 16; ++r) {
                const int rg0 = row0b + (r & 3) + 8 * (r >> 2);
                float e00 = __expf((acc00[r] - 1.0f) * INV_T);
                float e01 = __expf((acc01[r] - 1.0f) * INV_T);
                float e10 = __expf((acc10[r] - 1.0f) * INV_T);
                float e11 = __expf((acc11[r] - 1.0f) * INV_T);
                if (on_diag) {
                    if (rg0 == colg)           e00 = 0.f;
                    if (rg0 == colg + 32)      e01 = 0.f;
                    if (rg0 + 32 == colg)      e10 = 0.f;
                    if (rg0 + 32 == colg + 32) e11 = 0.f;
                }
                ps0[r] = e00 + e01;
                ps1[r] = e10 + e11;
            }
#pragma unroll
            for (int r = 0; r < 16; ++r) {
#pragma unroll
                for (int m = 1; m < 32; m <<= 1) {
                    ps0[r] += __shfl_xor(ps0[r], m);
                    ps1[r] += __shfl_xor(ps1[r], m);
                }
            }
            if (rlo == 0) {
#pragma unroll
                for (int r = 0; r < 16; ++r) {
                    const int rg0 = row0b + (r & 3) + 8 * (r >> 2);
                    atomicAdd(&rowsum[rg0], ps0[r]);
                    atomicAdd(&rowsum[rg0 + 32], ps1[r]);
                }
            }
            acc00 = f32x16{}; acc01 = f32x16{};
            acc10 = f32x16{}; acc11 = f32x16{};
        }
        ct = nct; kt = nkt;
    }
}

// ---------------- final: loss = mean(M + log S_i - pos) ---------------------
__global__ void kfinal(const float* __restrict__ rowsum, const float* __restrict__ pos,
                       float* __restrict__ out) {
    __shared__ float red[8];
    const int tid = threadIdx.x;
    float s = 0.f;
    for (int i = tid; i < N2; i += 512) {
        const int p = (i < NPAIR) ? i : i - NPAIR;
        s += INV_T + __logf(rowsum[i]) - pos[p];
    }
#pragma unroll
    for (int off = 32; off; off >>= 1) s += __shfl_xor(s, off);
    if ((tid & 63) == 0) red[tid >> 6] = s;
    __syncthreads();
    if (tid == 0) {
        float t = 0.f;
#pragma unroll
        for (int w = 0; w < 8; ++w) t += red[w];
        out[0] = t / (float)N2;
    }
}

extern "C" void kernel_launch(void* const* d_in, const int* in_sizes, int n_in,
                              void* d_out, int out_size, void* d_ws, size_t ws_size,
                              hipStream_t stream) {
    const float* z1 = (const float*)d_in[0];
    const float* z2 = (const float*)d_in[1];
    unsigned char* zq = (unsigned char*)d_ws;                         // 8192*768 fp8
    float* rowsum = (float*)((char*)d_ws + (size_t)N2 * DIM);         // 8192 f32
    float* pos = rowsum + N2;                                         // 4096 f32
    float* out = (float*)d_out;

    hipLaunchKernelGGL(knorm, dim3(N2 / 4), dim3(256), 0, stream, z1, z2, zq);
    hipLaunchKernelGGL(kpos, dim3(NPAIR / 4), dim3(256), 0, stream, zq, pos);
    hipMemsetAsync(rowsum, 0, N2 * sizeof(float), stream);
    hipLaunchKernelGGL(klse, dim3(NBI, NSTRIP), dim3(256), 0, stream, zq, rowsum);
    hipLaunchKernelGGL(kfinal, dim3(1), dim3(512), 0, stream, rowsum, pos, out);
}

// Round 12
// 131.181 us; speedup vs baseline: 1.7310x; 1.1941x over previous
//
#include <hip/hip_runtime.h>
#include <hip/hip_bf16.h>

#define NPAIR 4096
#define DIM   768            // fp8: 768 bytes per row
#define N2    8192
#define BM    128            // block rows (4 waves as 2x2, each 64x64)
#define BNB   128            // block cols per col-block
#define KBLK  64             // K tile bytes -> A,B tiles 8KB each; dbuf = 32KB
#define KITER (DIM / KBLK)   // 12
#define NSTRIP 16            // grid.y
#define CPB   ((N2 / BNB) / NSTRIP)    // 4 col-blocks per strip
#define NBI   (N2 / BM)      // 64
#define TOT   (CPB * KITER)  // 48 K-tile iterations per block

constexpr float INV_T = 1.0f / 0.07f;  // also the fixed softmax max M

typedef float f32x16 __attribute__((ext_vector_type(16)));
#define AS1 __attribute__((address_space(1)))
#define AS3 __attribute__((address_space(3)))

// ---------------- normalize: one wave per row, fp32 in -> fp8 e4m3 out ------
__global__ void knorm(const float* __restrict__ z1, const float* __restrict__ z2,
                      unsigned char* __restrict__ zq) {
    const int row  = blockIdx.x * 4 + (threadIdx.x >> 6);
    const int lane = threadIdx.x & 63;
    const float* src = (row < NPAIR) ? (z1 + (size_t)row * DIM)
                                     : (z2 + (size_t)(row - NPAIR) * DIM);
    float4 v[3];
    float ss = 0.f;
#pragma unroll
    for (int i = 0; i < 3; ++i) {
        v[i] = reinterpret_cast<const float4*>(src)[lane + 64 * i];
        ss += v[i].x * v[i].x + v[i].y * v[i].y + v[i].z * v[i].z + v[i].w * v[i].w;
    }
#pragma unroll
    for (int off = 32; off; off >>= 1) ss += __shfl_xor(ss, off);
    const float scale = 1.0f / fmaxf(sqrtf(ss), 1e-12f);
    unsigned int* dst = reinterpret_cast<unsigned int*>(zq + (size_t)row * DIM);
#pragma unroll
    for (int i = 0; i < 3; ++i) {
        unsigned int u = 0;
        u = __builtin_amdgcn_cvt_pk_fp8_f32(v[i].x * scale, v[i].y * scale, u, false);
        u = __builtin_amdgcn_cvt_pk_fp8_f32(v[i].z * scale, v[i].w * scale, u, true);
        dst[lane + 64 * i] = u;
    }
}

// ---------------- positive-pair dots from fp8 (consistent with klse) --------
__global__ void kpos(const unsigned char* __restrict__ zq, float* __restrict__ pos) {
    const int pair = blockIdx.x * 4 + (threadIdx.x >> 6);
    const int lane = threadIdx.x & 63;
    const unsigned int* a = reinterpret_cast<const unsigned int*>(zq + (size_t)pair * DIM);
    const unsigned int* b = reinterpret_cast<const unsigned int*>(zq + (size_t)(pair + NPAIR) * DIM);
    float s = 0.f;
#pragma unroll
    for (int i = 0; i < 3; ++i) {
        const unsigned int ua = a[lane + 64 * i];
        const unsigned int ub = b[lane + 64 * i];
        s += __builtin_amdgcn_cvt_f32_fp8(ua, 0) * __builtin_amdgcn_cvt_f32_fp8(ub, 0);
        s += __builtin_amdgcn_cvt_f32_fp8(ua, 1) * __builtin_amdgcn_cvt_f32_fp8(ub, 1);
        s += __builtin_amdgcn_cvt_f32_fp8(ua, 2) * __builtin_amdgcn_cvt_f32_fp8(ub, 2);
        s += __builtin_amdgcn_cvt_f32_fp8(ua, 3) * __builtin_amdgcn_cvt_f32_fp8(ub, 3);
    }
#pragma unroll
    for (int off = 32; off; off >>= 1) s += __shfl_xor(s, off);
    if (lane == 0) pos[pair] = s * INV_T;
}

// ---------------- main: R10 pipeline + fixed 4-way swizzle ------------------
// 2-phase dbuf (stage next FIRST, one vmcnt(0)+barrier per iter), 32KB LDS.
// Swizzle fix vs R10: granule slot = k ^ ((row>>1)&3). Offset mod 128B =
// (row&1)*64 + f*16 -> 8 distinct slots x 4 rows = 4-way conflict (R8 level),
// instead of R10's sw=row&3 (4 slots, 8-way, 3x conflict cycles).
__global__ __launch_bounds__(256, 3) void klse(const unsigned char* __restrict__ zq,
                                               float* __restrict__ rowsum) {
    __shared__ __align__(16) unsigned char As[2][BM * KBLK];   // 2 x 8 KB
    __shared__ __align__(16) unsigned char Bs[2][BM * KBLK];   // 2 x 8 KB
    const int tid  = threadIdx.x;
    const int wave = tid >> 6;
    const int lane = tid & 63;
    const int wr = wave >> 1, wc = wave & 1;
    const int hi = lane >> 5, rlo = lane & 31;
    const int bi = blockIdx.x;
    const int rb = bi * BM;

    const int sw  = (rlo >> 1) & 3;              // row-pair swizzle class
    const int raA = (wr * 64 + rlo) * KBLK;      // A sub 0 row base (bytes)
    const int raB = raA + 32 * KBLK;             // A sub 1
    const int caA = (wc * 64 + rlo) * KBLK;      // B sub 0 col base
    const int caB = caA + 32 * KBLK;             // B sub 1

    // stage K-tile (ct,kt) into buffer buf: 512 granules of 16B per matrix
    auto stage = [&](int ct, int kt, int buf) {
        const int c0 = (blockIdx.y * CPB + ct) * BNB;
        const int koff = kt * KBLK;
#pragma unroll
        for (int i = 0; i < 2; ++i) {
            const int g = i * 256 + tid;         // granule in [0,512)
            const int r = g >> 2, s = g & 3;
            const int ks = koff + ((s ^ ((r >> 1) & 3)) << 4);
            __builtin_amdgcn_global_load_lds(
                (const AS1 unsigned int*)(zq + (size_t)(rb + r) * DIM + ks),
                (AS3 unsigned int*)(&As[buf][g * 16]), 16, 0, 0);
            __builtin_amdgcn_global_load_lds(
                (const AS1 unsigned int*)(zq + (size_t)(c0 + r) * DIM + ks),
                (AS3 unsigned int*)(&Bs[buf][g * 16]), 16, 0, 0);
        }
    };

    f32x16 acc00 = {}, acc01 = {}, acc10 = {}, acc11 = {};

    stage(0, 0, 0);
    asm volatile("s_waitcnt vmcnt(0)" ::: "memory");
    __builtin_amdgcn_s_barrier();

    int ct = 0, kt = 0;
    for (int it = 0; it < TOT; ++it) {
        const int cur = it & 1;
        int nct = ct, nkt = kt + 1;
        if (nkt == KITER) { nkt = 0; ++nct; }
        if (it + 1 < TOT) stage(nct, nkt, cur ^ 1);   // issue next-tile loads FIRST

        // compute on buf[cur]: 4 K-steps x 2x2 subtiles
#pragma unroll
        for (int ts = 0; ts < 4; ++ts) {
            const int so = ((ts ^ sw) << 4) + (hi << 3);  // swizzled octet offset
            long a0 = *reinterpret_cast<const long*>(&As[cur][raA + so]);
            long a1 = *reinterpret_cast<const long*>(&As[cur][raB + so]);
            long b0 = *reinterpret_cast<const long*>(&Bs[cur][caA + so]);
            long b1 = *reinterpret_cast<const long*>(&Bs[cur][caB + so]);
            acc00 = __builtin_amdgcn_mfma_f32_32x32x16_fp8_fp8(a0, b0, acc00, 0, 0, 0);
            acc01 = __builtin_amdgcn_mfma_f32_32x32x16_fp8_fp8(a0, b1, acc01, 0, 0, 0);
            acc10 = __builtin_amdgcn_mfma_f32_32x32x16_fp8_fp8(a1, b0, acc10, 0, 0, 0);
            acc11 = __builtin_amdgcn_mfma_f32_32x32x16_fp8_fp8(a1, b1, acc11, 0, 0, 0);
        }

        asm volatile("s_waitcnt vmcnt(0)" ::: "memory");  // next buffer landed
        __builtin_amdgcn_s_barrier();                     // all reads of buf^1 done too

        if (kt == KITER - 1) {
            // ---------- epilogue for col-block ct: exp, mask, reduce --------
            const int cblk = blockIdx.y * CPB + ct;
            const bool on_diag = (cblk == bi);
            const int row0b = rb + wr * 64 + 4 * hi;
            const int colg  = cblk * BNB + wc * 64 + rlo;
            float ps0[16], ps1[16];
#pragma unroll
            for (int r = 0; r < 16; ++r) {
                const int rg0 = row0b + (r & 3) + 8 * (r >> 2);
                float e00 = __expf((acc00[r] - 1.0f) * INV_T);
                float e01 = __expf((acc01[r] - 1.0f) * INV_T);
                float e10 = __expf((acc10[r] - 1.0f) * INV_T);
                float e11 = __expf((acc11[r] - 1.0f) * INV_T);
                if (on_diag) {
                    if (rg0 == colg)           e00 = 0.f;
                    if (rg0 == colg + 32)      e01 = 0.f;
                    if (rg0 + 32 == colg)      e10 = 0.f;
                    if (rg0 + 32 == colg + 32) e11 = 0.f;
                }
                ps0[r] = e00 + e01;
                ps1[r] = e10 + e11;
            }
#pragma unroll
            for (int r = 0; r < 16; ++r) {
#pragma unroll
                for (int m = 1; m < 32; m <<= 1) {
                    ps0[r] += __shfl_xor(ps0[r], m);
                    ps1[r] += __shfl_xor(ps1[r], m);
                }
            }
            if (rlo == 0) {
#pragma unroll
                for (int r = 0; r < 16; ++r) {
                    const int rg0 = row0b + (r & 3) + 8 * (r >> 2);
                    atomicAdd(&rowsum[rg0], ps0[r]);
                    atomicAdd(&rowsum[rg0 + 32], ps1[r]);
                }
            }
            acc00 = f32x16{}; acc01 = f32x16{};
            acc10 = f32x16{}; acc11 = f32x16{};
        }
        ct = nct; kt = nkt;
    }
}

// ---------------- final: loss = mean(M + log S_i - pos) ---------------------
__global__ void kfinal(const float* __restrict__ rowsum, const float* __restrict__ pos,
                       float* __restrict__ out) {
    __shared__ float red[8];
    const int tid = threadIdx.x;
    float s = 0.f;
    for (int i = tid; i < N2; i += 512) {
        const int p = (i < NPAIR) ? i : i - NPAIR;
        s += INV_T + __logf(rowsum[i]) - pos[p];
    }
#pragma unroll
    for (int off = 32; off; off >>= 1) s += __shfl_xor(s, off);
    if ((tid & 63) == 0) red[tid >> 6] = s;
    __syncthreads();
    if (tid == 0) {
        float t = 0.f;
#pragma unroll
        for (int w = 0; w < 8; ++w) t += red[w];
        out[0] = t / (float)N2;
    }
}

extern "C" void kernel_launch(void* const* d_in, const int* in_sizes, int n_in,
                              void* d_out, int out_size, void* d_ws, size_t ws_size,
                              hipStream_t stream) {
    const float* z1 = (const float*)d_in[0];
    const float* z2 = (const float*)d_in[1];
    unsigned char* zq = (unsigned char*)d_ws;                         // 8192*768 fp8
    float* rowsum = (float*)((char*)d_ws + (size_t)N2 * DIM);         // 8192 f32
    float* pos = rowsum + N2;                                         // 4096 f32
    float* out = (float*)d_out;

    hipLaunchKernelGGL(knorm, dim3(N2 / 4), dim3(256), 0, stream, z1, z2, zq);
    hipLaunchKernelGGL(kpos, dim3(NPAIR / 4), dim3(256), 0, stream, zq, pos);
    hipMemsetAsync(rowsum, 0, N2 * sizeof(float), stream);
    hipLaunchKernelGGL(klse, dim3(NBI, NSTRIP), dim3(256), 0, stream, zq, rowsum);
    hipLaunchKernelGGL(kfinal, dim3(1), dim3(512), 0, stream, rowsum, pos, out);
}